// Round 2
// baseline (69.728 us; speedup 1.0000x reference)
//
#include <hip/hip_runtime.h>

// Problem constants
#define NB 16
#define NC 64
#define NM 6
#define ND 192
#define NHEADS 8
#define NCH 64
#define NINNER 512
#define PLANE 6144             // 64*96 floats per (b,c) plane
#define NCHUNK 8
#define CK 96                  // keys per chunk (8*96 = 768 unique keys/head)

// ---------------- Kernel A: 32x32 block means of x ----------------
// grid = NB*NC = 1024 blocks, 256 threads.
__global__ __launch_bounds__(256) void pool_kernel(const float* __restrict__ x,
                                                   float* __restrict__ xmean) {
    int bc = blockIdx.x;                       // b*64 + c
    const float4* p = (const float4*)(x + (size_t)bc * PLANE);   // 1536 float4
    int tid = threadIdx.x;
    float acc[6] = {0.f,0.f,0.f,0.f,0.f,0.f};
    #pragma unroll
    for (int k = 0; k < 6; ++k) {
        int idx4 = tid + k * 256;              // [0,1536)
        int hh = idx4 / 24;                    // row (24 float4 per row of 96)
        int w4 = idx4 - hh * 24;
        int j = (hh >> 5) * 3 + (w4 >> 3);     // pooling region
        float4 v = p[idx4];
        acc[j] += v.x + v.y + v.z + v.w;
    }
    int lane = tid & 63, wave = tid >> 6;
    #pragma unroll
    for (int j = 0; j < 6; ++j) {
        float v = acc[j];
        for (int off = 32; off > 0; off >>= 1) v += __shfl_down(v, off, 64);
        acc[j] = v;
    }
    __shared__ float part[4][6];
    if (lane == 0) {
        #pragma unroll
        for (int j = 0; j < 6; ++j) part[wave][j] = acc[j];
    }
    __syncthreads();
    if (tid < 6) {
        float s = part[0][tid] + part[1][tid] + part[2][tid] + part[3][tid];
        xmean[bc * 6 + tid] = s * (1.0f / 1024.0f);
    }
}

// ---------------- Kernel B: fused zn + q projection + attention ------------
// grid = NB*64 = 1024 blocks (b*64 + head*8 + chunk), 256 threads, 4 blk/CU.
// k-tile global loads are issued into registers FIRST; their latency hides
// under the zn / q compute (which only depends on xmean from kernel A).
// zn (6x192) is recomputed per block (dup x64 per batch, ~151M MAC chip-wide
// total = cheap) to kill the qr global round-trip and the zq launch.
//
// q reshape semantics (matches torch .view(b, heads, m, c) on (b,6,512)):
//   q[h][mi][ch] comes from flat = h*384 + mi*64 + ch:
//   z-row = flat>>9, wq-column = flat&511.   (6*512 == 8*6*64 mixes dims!)
__global__ __launch_bounds__(256, 4) void qattn_kernel(
    const float* __restrict__ x, const float* __restrict__ z,
    const float* __restrict__ conv_w, const float* __restrict__ conv_b,
    const float* __restrict__ wq, const float* __restrict__ bq,
    const float* __restrict__ xmean,
    float* __restrict__ znew, float* __restrict__ po, float* __restrict__ ps)
{
    int blk = blockIdx.x;                    // b*64 + c ; c = head*8 + chunk
    int b = blk >> 6, c = blk & 63;
    int head = c >> 3;
    int tid = threadIdx.x;

    __shared__ float k_lds[CK][NCH + 1];     // ~25KB, +1 pad -> 2-way (free)
    __shared__ float q_lds[NM][NCH];
    __shared__ float scratch[1740];          // phase2: zn(1152)+xm(384)
                                             // phase3: s(576)+pvp(1152)+den(6)

    // ---- issue k-tile loads early (6 x float4 per thread = 24 VGPR) ----
    float4 kreg[6];
    {
        const float4* k4 = (const float4*)(x + (size_t)blk * PLANE);
        #pragma unroll
        for (int r = 0; r < 6; ++r) kreg[r] = k4[tid + r * 256];
    }

    // ---- phase 2a: xmean[b,:,:] -> LDS ----
    float* zn_s = scratch;                   // [6][192]
    float* xm_s = scratch + 1152;            // [64][6]
    for (int i = tid; i < NC * NM; i += 256) xm_s[i] = xmean[b * (NC * NM) + i];
    __syncthreads();

    // ---- phase 2b: zn = z + conv(xmean) ----
    for (int i = tid; i < NM * ND; i += 256) {
        int m = i / ND, d = i - m * ND;
        float a = conv_b[d];
        const float* wr = conv_w + d * NC;
        #pragma unroll 16
        for (int cc = 0; cc < NC; ++cc) a += wr[cc] * xm_s[cc * NM + m];
        a += z[b * (NM * ND) + i];
        zn_s[i] = a;
        if (c == 0) znew[b * (NM * ND) + i] = a;   // uniform per block
    }
    __syncthreads();

    // ---- phase 2c: q slice for this head via the flat remap ----
    {
        for (int idx = tid; idx < NM * NCH; idx += 256) {
            int mi = idx >> 6, ch = idx & 63;
            int flat = head * (NM * NCH) + idx;      // h*384 + mi*64 + ch
            int mrow = flat >> 9;                    // z-row
            int col  = flat & 511;                   // wq column
            float a = bq[col];
            const float* zr = zn_s + mrow * ND;
            #pragma unroll 8
            for (int d = 0; d < ND; ++d) a += zr[d] * wq[d * NINNER + col];
            q_lds[mi][ch] = a;
        }
    }

    // ---- k regs -> LDS (waitcnt lands here; loads long since returned) ----
    #pragma unroll
    for (int r = 0; r < 6; ++r) {
        int idx4 = tid + r * 256;
        int u = idx4 >> 4, c4 = idx4 & 15;
        k_lds[u][c4 * 4 + 0] = kreg[r].x;
        k_lds[u][c4 * 4 + 1] = kreg[r].y;
        k_lds[u][c4 * 4 + 2] = kreg[r].z;
        k_lds[u][c4 * 4 + 3] = kreg[r].w;
    }
    __syncthreads();

    // ---- phase 3: attention partials (identical structure to prev fattn) --
    float* s_s   = scratch;                  // [6][96]
    float* pvp   = scratch + 576;            // [3][6][64]
    float* den_s = scratch + 1728;           // [6]

    if (tid < 192) {
        int mip = (tid & 1) * 3, u = tid >> 1;
        float a0 = 0.f, a1 = 0.f, a2 = 0.f;
        #pragma unroll
        for (int cc = 0; cc < NCH; ++cc) {
            float kv = k_lds[u][cc];
            a0 += kv * q_lds[mip + 0][cc];
            a1 += kv * q_lds[mip + 1][cc];
            a2 += kv * q_lds[mip + 2][cc];
        }
        s_s[(mip + 0) * CK + u] = __expf(a0 * 0.125f);
        s_s[(mip + 1) * CK + u] = __expf(a1 * 0.125f);
        s_s[(mip + 2) * CK + u] = __expf(a2 * 0.125f);
    }
    __syncthreads();

    int lane = tid & 63, wave = tid >> 6;
    #pragma unroll
    for (int rb = 0; rb < 2; ++rb) {
        int mi = rb * 4 + wave;
        if (mi < NM) {
            float v = s_s[mi * CK + lane] + ((lane < 32) ? s_s[mi * CK + 64 + lane] : 0.f);
            for (int msk = 1; msk < 64; msk <<= 1) v += __shfl_xor(v, msk, 64);
            if (lane == 0) den_s[mi] = v;
        }
    }

    float acc[NM] = {0.f,0.f,0.f,0.f,0.f,0.f};
    {
        int uq = tid >> 6, ch = tid & 63;
        int u0 = uq * 24;
        #pragma unroll 8
        for (int uu = u0; uu < u0 + 24; ++uu) {
            float kv = k_lds[uu][ch];
            #pragma unroll
            for (int mo = 0; mo < NM; ++mo) acc[mo] += s_s[mo * CK + uu] * kv;
        }
        if (uq > 0) {
            #pragma unroll
            for (int mo = 0; mo < NM; ++mo) pvp[((uq - 1) * NM + mo) * NCH + ch] = acc[mo];
        }
    }
    __syncthreads();
    if (tid < 64) {
        int ch = tid;
        #pragma unroll
        for (int mo = 0; mo < NM; ++mo) {
            float o = acc[mo] + pvp[(0 * NM + mo) * NCH + ch]
                              + pvp[(1 * NM + mo) * NCH + ch]
                              + pvp[(2 * NM + mo) * NCH + ch];
            po[(size_t)blk * (NM * NCH) + mo * NCH + ch] = o;
        }
    } else if (tid < 64 + NM) {
        ps[blk * NM + (tid - 64)] = den_s[tid - 64];
    }
}

// ---------------- Kernel D: combine (plain sum) + proj + residual ----------
// grid = NB*NM*4 = 384 blocks, 256 threads. Block = (b, m, colgroup of 48).
__global__ __launch_bounds__(256) void proj_kernel(const float* __restrict__ znew,
                                                   const float* __restrict__ po,
                                                   const float* __restrict__ ps,
                                                   const float* __restrict__ wo,
                                                   const float* __restrict__ bo,
                                                   float* __restrict__ out) {
    int blk = blockIdx.x;
    int cgrp = blk & 3, bm = blk >> 2;
    int b = bm / NM, m = bm - b * NM;
    int tid = threadIdx.x;
    __shared__ float orow[NINNER];
    __shared__ float part[3][48];

    for (int i = tid; i < NINNER; i += 256) {
        int h = i >> 6, ch = i & 63;
        int base = (b * NHEADS + h) * NCHUNK;
        float num = 0.f, den = 0.f;
        #pragma unroll
        for (int cu = 0; cu < NCHUNK; ++cu) {
            num += po[(size_t)(base + cu) * (NM * NCH) + m * NCH + ch];
            den += ps[(base + cu) * NM + m];
        }
        orow[i] = num / den;
    }
    __syncthreads();

    int ks = tid / 48;
    int colL = tid - ks * 48;
    float a = 0.f;
    int col = cgrp * 48 + ((tid < 192) ? colL : 0);
    if (tid < 192) {                          // 48 cols x 4-way split-K(128)
        int i0 = ks * 128;
        #pragma unroll 8
        for (int i = i0; i < i0 + 128; ++i) a += orow[i] * wo[i * ND + col];
        if (ks > 0) part[ks - 1][colL] = a;
    }
    __syncthreads();
    if (tid < 48) {                           // ks==0
        float tot = a + part[0][colL] + part[1][colL] + part[2][colL]
                  + bo[col] + znew[bm * ND + col];
        out[bm * ND + col] = tot;
    }
}

extern "C" void kernel_launch(void* const* d_in, const int* in_sizes, int n_in,
                              void* d_out, int out_size, void* d_ws, size_t ws_size,
                              hipStream_t stream) {
    const float* x      = (const float*)d_in[0];
    const float* z      = (const float*)d_in[1];
    const float* conv_w = (const float*)d_in[2];
    const float* conv_b = (const float*)d_in[3];
    const float* wq     = (const float*)d_in[4];
    const float* bq     = (const float*)d_in[5];
    const float* wo     = (const float*)d_in[6];
    const float* bo     = (const float*)d_in[7];
    float* out = (float*)d_out;

    float* ws    = (float*)d_ws;
    float* xmean = ws;               // 16*64*6          = 6144
    float* znew  = ws + 6144;        // 16*6*192         = 18432
    float* po    = ws + 24576;       // 1024*6*64        = 393216
    float* ps    = ws + 417792;      // 1024*6           = 6144

    pool_kernel<<<NB*NC, 256, 0, stream>>>(x, xmean);
    qattn_kernel<<<NB*NC, 256, 0, stream>>>(x, z, conv_w, conv_b, wq, bq,
                                            xmean, znew, po, ps);
    proj_kernel<<<NB*NM*4, 256, 0, stream>>>(znew, po, ps, wo, bo, out);
}

// Round 3
// 47.210 us; speedup vs baseline: 1.4770x; 1.4770x over previous
//
#include <hip/hip_runtime.h>

// Problem constants
#define NB 16
#define NC 64
#define NM 6
#define ND 192
#define NHEADS 8
#define NCH 64
#define NINNER 512
#define PLANE 6144             // 64*96 floats per (b,c) plane
#define XB (NC*PLANE)          // 393216 floats of x per batch
#define NKEY 768               // unique keys per head (dup-8 collapses in softmax)
#define NSEG 16                // segments per head
#define HC 48                  // keys per segment (16*48 = 768)
#define KP 68                  // k_lds row pad: float4-aligned, staggers banks by 4

// ---------------- Kernel A: 32x32 block means of x ----------------
// grid = NB*NC = 1024 blocks, 256 threads.
__global__ __launch_bounds__(256) void pool_kernel(const float* __restrict__ x,
                                                   float* __restrict__ xmean) {
    int bc = blockIdx.x;                       // b*64 + c
    const float4* p = (const float4*)(x + (size_t)bc * PLANE);   // 1536 float4
    int tid = threadIdx.x;
    float acc[6] = {0.f,0.f,0.f,0.f,0.f,0.f};
    #pragma unroll
    for (int k = 0; k < 6; ++k) {
        int idx4 = tid + k * 256;              // [0,1536)
        int hh = idx4 / 24;                    // row (24 float4 per row of 96)
        int w4 = idx4 - hh * 24;
        int j = (hh >> 5) * 3 + (w4 >> 3);     // pooling region
        float4 v = p[idx4];
        acc[j] += v.x + v.y + v.z + v.w;
    }
    int lane = tid & 63, wave = tid >> 6;
    #pragma unroll
    for (int j = 0; j < 6; ++j) {
        float v = acc[j];
        for (int off = 32; off > 0; off >>= 1) v += __shfl_down(v, off, 64);
        acc[j] = v;
    }
    __shared__ float part[4][6];
    if (lane == 0) {
        #pragma unroll
        for (int j = 0; j < 6; ++j) part[wave][j] = acc[j];
    }
    __syncthreads();
    if (tid < 6) {
        float s = part[0][tid] + part[1][tid] + part[2][tid] + part[3][tid];
        xmean[bc * 6 + tid] = s * (1.0f / 1024.0f);
    }
}

// ---------------- Kernel B: znew + q projection (permuted layout) ----------
// grid = NB*NM*8 = 768 blocks, 256 threads. Block = (b, m, colgroup of 64).
// (verbatim from the verified 37us version: weight columns read once per
//  block -> no duplicated L2 traffic)
__global__ __launch_bounds__(256) void zq_kernel(const float* __restrict__ z,
                                                 const float* __restrict__ conv_w,
                                                 const float* __restrict__ conv_b,
                                                 const float* __restrict__ wq,
                                                 const float* __restrict__ bq,
                                                 const float* __restrict__ xmean,
                                                 float* __restrict__ znew,
                                                 float* __restrict__ qr) {
    int blk = blockIdx.x;
    int cgrp = blk & 7, bm = blk >> 3;
    int b = bm / NM, m = bm - b * NM;
    int tid = threadIdx.x;
    __shared__ float xm[NC];
    __shared__ float zn[ND];
    __shared__ float qpart[3][64];
    if (tid < NC) xm[tid] = xmean[(b * NC + tid) * NM + m];
    __syncthreads();
    if (tid < ND) {
        float a = conv_b[tid];
        const float* wr = conv_w + tid * NC;
        #pragma unroll 16
        for (int c = 0; c < NC; ++c) a += wr[c] * xm[c];
        float v = z[bm * ND + tid] + a;
        zn[tid] = v;
        if (cgrp == 0) znew[bm * ND + tid] = v;
    }
    __syncthreads();
    int colL = tid & 63, ks = tid >> 6;          // 64 cols x 4-way split-K(48)
    int col = cgrp * 64 + colL;
    float a = (ks == 0) ? bq[col] : 0.f;
    int d0 = ks * 48;
    #pragma unroll 8
    for (int d = d0; d < d0 + 48; ++d) a += zn[d] * wq[d * NINNER + col];
    if (ks > 0) qpart[ks - 1][colL] = a;
    __syncthreads();
    if (ks == 0) {
        float tot = a + qpart[0][colL] + qpart[1][colL] + qpart[2][colL];
        int t = m * 8 + cgrp;                    // permuted q layout [b][48][64]
        qr[b * (48 * 64) + t * 64 + colL] = tot;
    }
}

// ---------------- Kernel C: attention partials, v2 ----------------
// grid = NB*NHEADS*NSEG = 2048 blocks, 256 threads, 8 blocks/CU (15.8KB LDS).
// 48-key segments: halved per-block critical path, 2 grid rounds -> load
// latency of round 2 hides under round 1 compute. float4 LDS reads in dots;
// PV needs no partial buffer (wave owns 16-col slice, shfl_xor combine).
// No max-subtraction (|s| < ~2) -> partials are plain sums; proj combines.
__global__ __launch_bounds__(256, 8) void fattn_kernel(const float* __restrict__ x,
                                                       const float* __restrict__ qr,
                                                       float* __restrict__ po,
                                                       float* __restrict__ ps) {
    int blk = blockIdx.x;                    // ((b*8+head)*16 + seg)
    int seg = blk & 15, bh = blk >> 4;
    int head = bh & 7, b = bh >> 3;
    int tid = threadIdx.x;
    __shared__ float k_lds[HC][KP];          // 13056 B
    __shared__ float q_lds[NM][NCH];         // 1536 B
    __shared__ float s_lds[NM][52];          // 1248 B
    const float* kbase = x + (size_t)b * XB + (size_t)(head * NKEY + seg * HC) * NCH;

    // q load (coalesced; qr pre-permuted)
    for (int i = tid; i < NM * NCH; i += 256) {
        int mi = i >> 6, ch = i & 63;
        q_lds[mi][ch] = qr[b * (48 * 64) + (head * NM + mi) * 64 + ch];
    }
    // k tile: 48 rows x 16 float4 = 768 float4, 3 per thread
    const float4* k4 = (const float4*)kbase;
    #pragma unroll
    for (int r = 0; r < 3; ++r) {
        int i = tid + r * 256;
        int row = i >> 4, c4 = i & 15;
        float4 v = k4[i];
        *(float4*)&k_lds[row][c4 * 4] = v;
    }
    __syncthreads();

    // dots + exp: 96 threads; thread = (k-row u, m-trio). float4 LDS reads.
    if (tid < 96) {
        int u = tid >> 1, mip = (tid & 1) * 3;
        float a0 = 0.f, a1 = 0.f, a2 = 0.f;
        #pragma unroll
        for (int c = 0; c < 16; ++c) {
            float4 kv = *(const float4*)&k_lds[u][c * 4];
            float4 q0 = *(const float4*)&q_lds[mip + 0][c * 4];
            float4 q1 = *(const float4*)&q_lds[mip + 1][c * 4];
            float4 q2 = *(const float4*)&q_lds[mip + 2][c * 4];
            a0 += kv.x*q0.x + kv.y*q0.y + kv.z*q0.z + kv.w*q0.w;
            a1 += kv.x*q1.x + kv.y*q1.y + kv.z*q1.z + kv.w*q1.w;
            a2 += kv.x*q2.x + kv.y*q2.y + kv.z*q2.z + kv.w*q2.w;
        }
        s_lds[mip + 0][u] = __expf(a0 * 0.125f);
        s_lds[mip + 1][u] = __expf(a1 * 0.125f);
        s_lds[mip + 2][u] = __expf(a2 * 0.125f);
    }
    __syncthreads();

    int lane = tid & 63, wave = tid >> 6;

    // denominators -> ps (6 rows of 48; waves 0-3 then 0-1)
    #pragma unroll
    for (int rb = 0; rb < 2; ++rb) {
        int mi = rb * 4 + wave;
        if (mi < NM) {
            float v = (lane < HC) ? s_lds[mi][lane] : 0.f;
            for (int msk = 1; msk < 64; msk <<= 1) v += __shfl_xor(v, msk, 64);
            if (lane == 0) ps[blk * NM + mi] = v;
        }
    }

    // PV: wave w owns cols [w*16, w*16+16); lane = (row-group rg, col chL).
    // Each lane accumulates 12 of 48 rows; 2-step shfl_xor folds the 4 rgs.
    {
        int chL = lane & 15, rg = lane >> 4;
        int ch = wave * 16 + chL;
        float acc[NM] = {0.f,0.f,0.f,0.f,0.f,0.f};
        #pragma unroll
        for (int i = 0; i < 12; ++i) {
            int u = rg + i * 4;
            float kv = k_lds[u][ch];
            #pragma unroll
            for (int mo = 0; mo < NM; ++mo) acc[mo] += s_lds[mo][u] * kv;
        }
        #pragma unroll
        for (int mo = 0; mo < NM; ++mo) {
            float v = acc[mo];
            v += __shfl_xor(v, 16, 64);
            v += __shfl_xor(v, 32, 64);
            if (rg == 0) po[(size_t)blk * (NM * NCH) + mo * NCH + ch] = v;
        }
    }
}

// ---------------- Kernel D: combine (plain sum) + proj + residual ----------
// grid = NB*NM*4 = 384 blocks, 256 threads. Block = (b, m, colgroup of 48).
__global__ __launch_bounds__(256) void proj_kernel(const float* __restrict__ znew,
                                                   const float* __restrict__ po,
                                                   const float* __restrict__ ps,
                                                   const float* __restrict__ wo,
                                                   const float* __restrict__ bo,
                                                   float* __restrict__ out) {
    int blk = blockIdx.x;
    int cgrp = blk & 3, bm = blk >> 2;
    int b = bm / NM, m = bm - b * NM;
    int tid = threadIdx.x;
    __shared__ float orow[NINNER];
    __shared__ float part[3][48];

    for (int i = tid; i < NINNER; i += 256) {
        int h = i >> 6, ch = i & 63;
        int base = (b * NHEADS + h) * NSEG;
        float num = 0.f, den = 0.f;
        #pragma unroll
        for (int cu = 0; cu < NSEG; ++cu) {
            num += po[(size_t)(base + cu) * (NM * NCH) + m * NCH + ch];
            den += ps[(base + cu) * NM + m];
        }
        orow[i] = num / den;
    }
    __syncthreads();

    int ks = tid / 48;
    int colL = tid - ks * 48;
    float a = 0.f;
    int col = cgrp * 48 + ((tid < 192) ? colL : 0);
    if (tid < 192) {                          // 48 cols x 4-way split-K(128)
        int i0 = ks * 128;
        #pragma unroll 8
        for (int i = i0; i < i0 + 128; ++i) a += orow[i] * wo[i * ND + col];
        if (ks > 0) part[ks - 1][colL] = a;
    }
    __syncthreads();
    if (tid < 48) {                           // ks==0
        float tot = a + part[0][colL] + part[1][colL] + part[2][colL]
                  + bo[col] + znew[bm * ND + col];
        out[bm * ND + col] = tot;
    }
}

extern "C" void kernel_launch(void* const* d_in, const int* in_sizes, int n_in,
                              void* d_out, int out_size, void* d_ws, size_t ws_size,
                              hipStream_t stream) {
    const float* x      = (const float*)d_in[0];
    const float* z      = (const float*)d_in[1];
    const float* conv_w = (const float*)d_in[2];
    const float* conv_b = (const float*)d_in[3];
    const float* wq     = (const float*)d_in[4];
    const float* bq     = (const float*)d_in[5];
    const float* wo     = (const float*)d_in[6];
    const float* bo     = (const float*)d_in[7];
    float* out = (float*)d_out;

    float* ws    = (float*)d_ws;
    float* xmean = ws;               // 16*64*6          = 6144
    float* znew  = ws + 6144;        // 16*6*192         = 18432
    float* qr    = ws + 24576;       // 16*48*64         = 49152
    float* po    = ws + 73728;       // 2048*6*64        = 786432
    float* ps    = ws + 860160;      // 2048*6           = 12288

    pool_kernel<<<NB*NC, 256, 0, stream>>>(x, xmean);
    zq_kernel<<<NB*NM*8, 256, 0, stream>>>(z, conv_w, conv_b, wq, bq, xmean, znew, qr);
    fattn_kernel<<<NB*NHEADS*NSEG, 256, 0, stream>>>(x, qr, po, ps);
    proj_kernel<<<NB*NM*4, 256, 0, stream>>>(znew, po, ps, wo, bo, out);
}

// Round 4
// 36.727 us; speedup vs baseline: 1.8985x; 1.2854x over previous
//
#include <hip/hip_runtime.h>

// Problem constants
#define NB 16
#define NC 64
#define NM 6
#define ND 192
#define NHEADS 8
#define NCH 64
#define NINNER 512
#define PLANE 6144             // 64*96 floats per (b,c) plane
#define XB (NC*PLANE)          // 393216 floats of x per batch
#define NKEY 768               // unique keys per head (dup-8 collapses in softmax)
#define NCHUNK 8
#define CK 96                  // keys per chunk (8*96 = 768)
#define KP 68                  // k/q row pitch: 272B, 16B-aligned, bank-staggered
#define SP 100                 // s row pitch: 400B, 16B-aligned

// ---------------- Kernel A: 32x32 block means of x ----------------
// grid = NB*NC = 1024 blocks, 256 threads.  (verbatim from 36.8us baseline)
__global__ __launch_bounds__(256) void pool_kernel(const float* __restrict__ x,
                                                   float* __restrict__ xmean) {
    int bc = blockIdx.x;                       // b*64 + c
    const float4* p = (const float4*)(x + (size_t)bc * PLANE);   // 1536 float4
    int tid = threadIdx.x;
    float acc[6] = {0.f,0.f,0.f,0.f,0.f,0.f};
    #pragma unroll
    for (int k = 0; k < 6; ++k) {
        int idx4 = tid + k * 256;              // [0,1536)
        int hh = idx4 / 24;                    // row (24 float4 per row of 96)
        int w4 = idx4 - hh * 24;
        int j = (hh >> 5) * 3 + (w4 >> 3);     // pooling region
        float4 v = p[idx4];
        acc[j] += v.x + v.y + v.z + v.w;
    }
    int lane = tid & 63, wave = tid >> 6;
    #pragma unroll
    for (int j = 0; j < 6; ++j) {
        float v = acc[j];
        for (int off = 32; off > 0; off >>= 1) v += __shfl_down(v, off, 64);
        acc[j] = v;
    }
    __shared__ float part[4][6];
    if (lane == 0) {
        #pragma unroll
        for (int j = 0; j < 6; ++j) part[wave][j] = acc[j];
    }
    __syncthreads();
    if (tid < 6) {
        float s = part[0][tid] + part[1][tid] + part[2][tid] + part[3][tid];
        xmean[bc * 6 + tid] = s * (1.0f / 1024.0f);
    }
}

// ---------------- Kernel B: znew + q projection (permuted layout) ----------
// grid = NB*NM*8 = 768 blocks, 256 threads.  (verbatim from 36.8us baseline)
__global__ __launch_bounds__(256) void zq_kernel(const float* __restrict__ z,
                                                 const float* __restrict__ conv_w,
                                                 const float* __restrict__ conv_b,
                                                 const float* __restrict__ wq,
                                                 const float* __restrict__ bq,
                                                 const float* __restrict__ xmean,
                                                 float* __restrict__ znew,
                                                 float* __restrict__ qr) {
    int blk = blockIdx.x;
    int cgrp = blk & 7, bm = blk >> 3;
    int b = bm / NM, m = bm - b * NM;
    int tid = threadIdx.x;
    __shared__ float xm[NC];
    __shared__ float zn[ND];
    __shared__ float qpart[3][64];
    if (tid < NC) xm[tid] = xmean[(b * NC + tid) * NM + m];
    __syncthreads();
    if (tid < ND) {
        float a = conv_b[tid];
        const float* wr = conv_w + tid * NC;
        #pragma unroll 16
        for (int c = 0; c < NC; ++c) a += wr[c] * xm[c];
        float v = z[bm * ND + tid] + a;
        zn[tid] = v;
        if (cgrp == 0) znew[bm * ND + tid] = v;
    }
    __syncthreads();
    int colL = tid & 63, ks = tid >> 6;          // 64 cols x 4-way split-K(48)
    int col = cgrp * 64 + colL;
    float a = (ks == 0) ? bq[col] : 0.f;
    int d0 = ks * 48;
    #pragma unroll 8
    for (int d = d0; d < d0 + 48; ++d) a += zn[d] * wq[d * NINNER + col];
    if (ks > 0) qpart[ks - 1][colL] = a;
    __syncthreads();
    if (ks == 0) {
        float tot = a + qpart[0][colL] + qpart[1][colL] + qpart[2][colL];
        int t = m * 8 + cgrp;                    // permuted q layout [b][48][64]
        qr[b * (48 * 64) + t * 64 + colL] = tot;
    }
}

// ---------------- Kernel C: attention partials, v3 (LDS-instr diet) -------
// grid = NB*NHEADS*NCHUNK = 1024 blocks, 256 threads, 4 blocks/CU.
// Same interface/grid as the 36.8us baseline; only internals changed:
//  - dots: 48 threads x (4 rows x 3 m), float4 LDS reads. Rows strided by 24
//    -> quarter-wave hits 8 row-addresses at pitch 68 covering all 32 banks
//    exactly once (conflict-free b128). 112 b128/block vs 768 b32/block.
//  - PV: s read as broadcast float4 (36 b128 + 24 b32 per thread vs 168 b32).
//  - k staged with aligned float4 LDS writes.
// No max-subtraction (|s| < ~2, exp safe in f32) -> partials are plain sums.
__global__ __launch_bounds__(256, 4) void fattn_kernel(const float* __restrict__ x,
                                                       const float* __restrict__ qr,
                                                       float* __restrict__ po,
                                                       float* __restrict__ ps) {
    int blk = blockIdx.x;                    // ((b*8+head)*8+chunk)
    int chunk = blk & 7, bh = blk >> 3;
    int head = bh & 7, b = bh >> 3;
    int tid = threadIdx.x;
    __shared__ float k_lds[CK][KP];          // 96x68x4 = 26112 B
    __shared__ float q_lds[NM][KP];          // 6x68x4  =  1632 B (cols 0-63 used)
    __shared__ float s_lds[NM][SP];          // 6x100x4 =  2400 B
    __shared__ float pvp[3][NM][NCH];        //            4608 B
    const float* kbase = x + (size_t)b * XB + (size_t)(head * NKEY + chunk * CK) * NCH;

    // q load (coalesced; qr pre-permuted)
    for (int i = tid; i < NM * NCH; i += 256) {
        int mi = i >> 6, ch = i & 63;
        q_lds[mi][ch] = qr[b * (48 * 64) + (head * NM + mi) * 64 + ch];
    }
    // k tile: 96 rows x 16 float4 = 1536, aligned float4 LDS writes
    const float4* k4 = (const float4*)kbase;
    #pragma unroll
    for (int r = 0; r < 6; ++r) {
        int i = tid + r * 256;
        int row = i >> 4, c4 = i & 15;
        float4 v = k4[i];
        *(float4*)&k_lds[row][c4 * 4] = v;
    }
    __syncthreads();

    // ---- dots + exp: 48 threads, thread = (t in [0,24), mip in {0,3}) ----
    // rows u = t + 24j, j=0..3 ; 3 query rows mip..mip+2
    if (tid < 48) {
        int t = tid >> 1, mip = (tid & 1) * 3;
        float a[4][3];
        #pragma unroll
        for (int j = 0; j < 4; ++j) { a[j][0] = 0.f; a[j][1] = 0.f; a[j][2] = 0.f; }
        #pragma unroll 4
        for (int c = 0; c < 16; ++c) {
            float4 q0 = *(const float4*)&q_lds[mip + 0][c * 4];
            float4 q1 = *(const float4*)&q_lds[mip + 1][c * 4];
            float4 q2 = *(const float4*)&q_lds[mip + 2][c * 4];
            #pragma unroll
            for (int j = 0; j < 4; ++j) {
                float4 kv = *(const float4*)&k_lds[t + 24 * j][c * 4];
                a[j][0] += kv.x*q0.x + kv.y*q0.y + kv.z*q0.z + kv.w*q0.w;
                a[j][1] += kv.x*q1.x + kv.y*q1.y + kv.z*q1.z + kv.w*q1.w;
                a[j][2] += kv.x*q2.x + kv.y*q2.y + kv.z*q2.z + kv.w*q2.w;
            }
        }
        #pragma unroll
        for (int j = 0; j < 4; ++j) {
            s_lds[mip + 0][t + 24 * j] = __expf(a[j][0] * 0.125f);
            s_lds[mip + 1][t + 24 * j] = __expf(a[j][1] * 0.125f);
            s_lds[mip + 2][t + 24 * j] = __expf(a[j][2] * 0.125f);
        }
    }
    __syncthreads();

    int lane = tid & 63, wave = tid >> 6;

    // ---- denominators -> ps (6 rows of 96; waves 0-3 then 0-1) ----
    #pragma unroll
    for (int rb = 0; rb < 2; ++rb) {
        int mi = rb * 4 + wave;
        if (mi < NM) {
            float v = s_lds[mi][lane] + ((lane < 32) ? s_lds[mi][64 + lane] : 0.f);
            for (int msk = 1; msk < 64; msk <<= 1) v += __shfl_xor(v, msk, 64);
            if (lane == 0) ps[blk * NM + mi] = v;
        }
    }

    // ---- PV: thread (uq = tid>>6, ch = tid&63); s via broadcast float4 ----
    float acc[NM] = {0.f,0.f,0.f,0.f,0.f,0.f};
    {
        int uq = tid >> 6, ch = tid & 63;
        int u0 = uq * 24;
        #pragma unroll
        for (int ub = 0; ub < 6; ++ub) {
            float4 s0 = *(const float4*)&s_lds[0][u0 + ub * 4];
            float4 s1 = *(const float4*)&s_lds[1][u0 + ub * 4];
            float4 s2 = *(const float4*)&s_lds[2][u0 + ub * 4];
            float4 s3 = *(const float4*)&s_lds[3][u0 + ub * 4];
            float4 s4 = *(const float4*)&s_lds[4][u0 + ub * 4];
            float4 s5 = *(const float4*)&s_lds[5][u0 + ub * 4];
            float kv0 = k_lds[u0 + ub * 4 + 0][ch];
            float kv1 = k_lds[u0 + ub * 4 + 1][ch];
            float kv2 = k_lds[u0 + ub * 4 + 2][ch];
            float kv3 = k_lds[u0 + ub * 4 + 3][ch];
            acc[0] += s0.x*kv0 + s0.y*kv1 + s0.z*kv2 + s0.w*kv3;
            acc[1] += s1.x*kv0 + s1.y*kv1 + s1.z*kv2 + s1.w*kv3;
            acc[2] += s2.x*kv0 + s2.y*kv1 + s2.z*kv2 + s2.w*kv3;
            acc[3] += s3.x*kv0 + s3.y*kv1 + s3.z*kv2 + s3.w*kv3;
            acc[4] += s4.x*kv0 + s4.y*kv1 + s4.z*kv2 + s4.w*kv3;
            acc[5] += s5.x*kv0 + s5.y*kv1 + s5.z*kv2 + s5.w*kv3;
        }
        if (uq > 0) {
            #pragma unroll
            for (int mo = 0; mo < NM; ++mo) pvp[uq - 1][mo][ch] = acc[mo];
        }
    }
    __syncthreads();
    if (tid < 64) {                          // uq==0 threads finalize
        int ch = tid;
        #pragma unroll
        for (int mo = 0; mo < NM; ++mo) {
            float o = acc[mo] + pvp[0][mo][ch] + pvp[1][mo][ch] + pvp[2][mo][ch];
            po[(size_t)blk * (NM * NCH) + mo * NCH + ch] = o;
        }
    }
}

// ---------------- Kernel D: combine (plain sum) + proj + residual ----------
// grid = NB*NM*4 = 384 blocks, 256 threads.  (verbatim from 36.8us baseline)
__global__ __launch_bounds__(256) void proj_kernel(const float* __restrict__ znew,
                                                   const float* __restrict__ po,
                                                   const float* __restrict__ ps,
                                                   const float* __restrict__ wo,
                                                   const float* __restrict__ bo,
                                                   float* __restrict__ out) {
    int blk = blockIdx.x;
    int cgrp = blk & 3, bm = blk >> 2;
    int b = bm / NM, m = bm - b * NM;
    int tid = threadIdx.x;
    __shared__ float orow[NINNER];
    __shared__ float part[3][48];

    for (int i = tid; i < NINNER; i += 256) {
        int h = i >> 6, ch = i & 63;
        int base = (b * NHEADS + h) * NCHUNK;
        float num = 0.f, den = 0.f;
        #pragma unroll
        for (int c = 0; c < NCHUNK; ++c) {
            num += po[(size_t)(base + c) * (NM * NCH) + m * NCH + ch];
            den += ps[(base + c) * NM + m];
        }
        orow[i] = num / den;
    }
    __syncthreads();

    int ks = tid / 48;
    int colL = tid - ks * 48;
    float a = 0.f;
    int col = cgrp * 48 + ((tid < 192) ? colL : 0);
    if (tid < 192) {                          // 48 cols x 4-way split-K(128)
        int i0 = ks * 128;
        #pragma unroll 8
        for (int i = i0; i < i0 + 128; ++i) a += orow[i] * wo[i * ND + col];
        if (ks > 0) part[ks - 1][colL] = a;
    }
    __syncthreads();
    if (tid < 48) {                           // ks==0
        float tot = a + part[0][colL] + part[1][colL] + part[2][colL]
                  + bo[col] + znew[bm * ND + col];
        out[bm * ND + col] = tot;
    }
}

extern "C" void kernel_launch(void* const* d_in, const int* in_sizes, int n_in,
                              void* d_out, int out_size, void* d_ws, size_t ws_size,
                              hipStream_t stream) {
    const float* x      = (const float*)d_in[0];
    const float* z      = (const float*)d_in[1];
    const float* conv_w = (const float*)d_in[2];
    const float* conv_b = (const float*)d_in[3];
    const float* wq     = (const float*)d_in[4];
    const float* bq     = (const float*)d_in[5];
    const float* wo     = (const float*)d_in[6];
    const float* bo     = (const float*)d_in[7];
    float* out = (float*)d_out;

    float* ws    = (float*)d_ws;
    float* xmean = ws;              // 16*64*6          = 6144
    float* znew  = ws + 6144;       // 16*6*192         = 18432
    float* qr    = ws + 24576;      // 16*48*64         = 49152
    float* po    = ws + 73728;      // 1024*6*64        = 393216
    float* ps    = ws + 466944;     // 1024*6           = 6144

    pool_kernel<<<NB*NC, 256, 0, stream>>>(x, xmean);
    zq_kernel<<<NB*NM*8, 256, 0, stream>>>(z, conv_w, conv_b, wq, bq, xmean, znew, qr);
    fattn_kernel<<<NB*NHEADS*NCHUNK, 256, 0, stream>>>(x, qr, po, ps);
    proj_kernel<<<NB*NM*4, 256, 0, stream>>>(znew, po, ps, wo, bo, out);
}

// Round 6
// 36.657 us; speedup vs baseline: 1.9022x; 1.0019x over previous
//
#include <hip/hip_runtime.h>
#include <hip/hip_cooperative_groups.h>

namespace cg = cooperative_groups;

// Problem constants
#define NB 16
#define NC 64
#define NM 6
#define ND 192
#define NHEADS 8
#define NCH 64
#define NINNER 512
#define PLANE 6144             // 64*96 floats per (b,c) plane
#define XB (NC*PLANE)
#define NKEY 768               // unique keys per head (dup-8 collapses in softmax)
#define NCHUNK 8
#define CK 96                  // keys per chunk (8*96 = 768)
#define KP 68                  // fallback-fattn k/q pitch
#define SP 100                 // fallback-fattn s pitch

// ---- fused-kernel LDS carve (floats, per sub-block) ----
#define KP2 72                 // k row pitch (72%32=8 -> <=2-way in PV)
#define KSZ (CK*KP2)           // 6912
#define QOFF 6912              // q: 6*64 = 384
#define SOFF 7296              // s: 6*96 = 576
#define SUBF 7872              // per-sub total; x2 = 62976 B static LDS

// =====================================================================
// Fused cooperative kernel: 512 blocks x 512 threads, 2 blocks/CU.
// Block bc, sub s (threads s*256..): plane p = bc + s*512 (p = b*64 + c).
//   P1: load plane -> k region (persists!) + pool means -> xmean
//   P2: 768 zq tasks (task = bc + s*512): zn = z+conv(xmean); q proj -> qr
//   P3: attention partials on the LDS-resident k-tile -> po, ps
//   P4: 384 proj tasks (sub 0, bc<384): combine + out-proj + residual
// x is read from HBM exactly once; no inter-kernel gaps.
// =====================================================================
__global__ __launch_bounds__(512, 4) void fused_kernel(
    const float* __restrict__ x, const float* __restrict__ z,
    const float* __restrict__ conv_w, const float* __restrict__ conv_b,
    const float* __restrict__ wq, const float* __restrict__ bq,
    const float* __restrict__ wo, const float* __restrict__ bo,
    float* __restrict__ xmean, float* __restrict__ znew,
    float* __restrict__ qr, float* __restrict__ po, float* __restrict__ ps,
    float* __restrict__ out)
{
    cg::grid_group grid = cg::this_grid();
    int bc = blockIdx.x;
    int tid = threadIdx.x;
    int sub = tid >> 8, ttid = tid & 255;
    int lane = tid & 63;
    int wsub = (tid >> 6) & 3;               // wave index within sub-block

    __shared__ __align__(16) float smem[2 * SUBF];
    float* S = smem + sub * SUBF;            // this sub-block's working set

    int plane = bc + sub * 512;              // = b*64 + c
    int pb = plane >> 6, pc = plane & 63;
    int phead = pc >> 3;

    // ================= Phase 1: plane load + pool =================
    {
        const float4* p = (const float4*)(x + (size_t)plane * PLANE); // 1536 f4
        float4 v[6];
        #pragma unroll
        for (int r = 0; r < 6; ++r) v[r] = p[ttid + r * 256];
        float acc[6] = {0.f,0.f,0.f,0.f,0.f,0.f};
        #pragma unroll
        for (int r = 0; r < 6; ++r) {
            int idx4 = ttid + r * 256;               // [0,1536)
            int hh = idx4 / 24;                      // pool view row (of 96 f)
            int w4 = idx4 - hh * 24;
            int j = (hh >> 5) * 3 + (w4 >> 3);       // pooling region
            acc[j] += v[r].x + v[r].y + v[r].z + v[r].w;
            int u = idx4 >> 4, c4 = idx4 & 15;       // attn view [96][64]
            *(float4*)&S[u * KP2 + c4 * 4] = v[r];
        }
        #pragma unroll
        for (int j = 0; j < 6; ++j) {
            float s = acc[j];
            for (int off = 32; off > 0; off >>= 1) s += __shfl_down(s, off, 64);
            acc[j] = s;
        }
        if (lane == 0) {
            #pragma unroll
            for (int j = 0; j < 6; ++j) S[QOFF + wsub * 6 + j] = acc[j];
        }
        __syncthreads();
        if (ttid < 6) {
            float s = S[QOFF + ttid] + S[QOFF + 6 + ttid]
                    + S[QOFF + 12 + ttid] + S[QOFF + 18 + ttid];
            xmean[plane * 6 + ttid] = s * (1.0f / 1024.0f);
        }
    }
    __threadfence();
    grid.sync();
    __threadfence();

    // ================= Phase 2: znew + q projection (768 tasks) ===========
    {
        int task = bc + sub * 512;
        bool act = task < 768;
        int cgrp = task & 7, bm = task >> 3;
        int b = bm / NM, m = bm - b * NM;
        float* xm = S + QOFF;                // 64
        float* zn = S + QOFF + 64;           // 192
        float* qp = S + QOFF + 256;          // 3*64   (all within [QOFF,SUBF))
        if (act && ttid < NC) xm[ttid] = xmean[(b * NC + ttid) * NM + m];
        __syncthreads();
        if (act && ttid < ND) {
            float a = conv_b[ttid];
            const float* wr = conv_w + ttid * NC;
            #pragma unroll 16
            for (int cc = 0; cc < NC; ++cc) a += wr[cc] * xm[cc];
            float vv = z[bm * ND + ttid] + a;
            zn[ttid] = vv;
            if (cgrp == 0) znew[bm * ND + ttid] = vv;
        }
        __syncthreads();
        int colL = ttid & 63, ks = ttid >> 6;        // 64 cols x 4-way K(48)
        int col = cgrp * 64 + colL;
        float a = 0.f;
        if (act) {
            a = (ks == 0) ? bq[col] : 0.f;
            int d0 = ks * 48;
            #pragma unroll 8
            for (int d = d0; d < d0 + 48; ++d) a += zn[d] * wq[d * NINNER + col];
            if (ks > 0) qp[(ks - 1) * 64 + colL] = a;
        }
        __syncthreads();
        if (act && ks == 0) {
            float tot = a + qp[colL] + qp[64 + colL] + qp[128 + colL];
            int t = m * 8 + cgrp;                    // permuted q layout
            qr[b * (48 * 64) + t * 64 + colL] = tot;
        }
    }
    __threadfence();
    grid.sync();
    __threadfence();

    // ================= Phase 3: attention partials (k is LDS-resident) ====
    {
        // q load (coalesced; qr pre-permuted)
        for (int i = ttid; i < NM * NCH; i += 256) {
            int mi = i >> 6, ch = i & 63;
            S[QOFF + mi * 64 + ch] = qr[pb * (48 * 64) + (phead * NM + mi) * 64 + ch];
        }
        __syncthreads();

        // dots + exp: 48 threads/sub, thread = (t in [0,24), mip in {0,3});
        // rows u = t + 24j
        if (ttid < 48) {
            int t = ttid >> 1, mip = (ttid & 1) * 3;
            float a[4][3];
            #pragma unroll
            for (int j = 0; j < 4; ++j) { a[j][0]=0.f; a[j][1]=0.f; a[j][2]=0.f; }
            #pragma unroll 4
            for (int cc = 0; cc < 16; ++cc) {
                float4 q0 = *(const float4*)&S[QOFF + (mip + 0) * 64 + cc * 4];
                float4 q1 = *(const float4*)&S[QOFF + (mip + 1) * 64 + cc * 4];
                float4 q2 = *(const float4*)&S[QOFF + (mip + 2) * 64 + cc * 4];
                #pragma unroll
                for (int j = 0; j < 4; ++j) {
                    float4 kv = *(const float4*)&S[(t + 24 * j) * KP2 + cc * 4];
                    a[j][0] += kv.x*q0.x + kv.y*q0.y + kv.z*q0.z + kv.w*q0.w;
                    a[j][1] += kv.x*q1.x + kv.y*q1.y + kv.z*q1.z + kv.w*q1.w;
                    a[j][2] += kv.x*q2.x + kv.y*q2.y + kv.z*q2.z + kv.w*q2.w;
                }
            }
            #pragma unroll
            for (int j = 0; j < 4; ++j) {
                S[SOFF + (mip + 0) * 96 + t + 24 * j] = __expf(a[j][0] * 0.125f);
                S[SOFF + (mip + 1) * 96 + t + 24 * j] = __expf(a[j][1] * 0.125f);
                S[SOFF + (mip + 2) * 96 + t + 24 * j] = __expf(a[j][2] * 0.125f);
            }
        }
        __syncthreads();

        // denominators -> ps (6 rows of 96; sub-waves 0-3 then 0-1)
        #pragma unroll
        for (int rb = 0; rb < 2; ++rb) {
            int mi = rb * 4 + wsub;
            if (mi < NM) {
                float v = S[SOFF + mi * 96 + lane]
                        + ((lane < 32) ? S[SOFF + mi * 96 + 64 + lane] : 0.f);
                for (int msk = 1; msk < 64; msk <<= 1) v += __shfl_xor(v, msk, 64);
                if (lane == 0) ps[plane * NM + mi] = v;
            }
        }

        // PV: wave owns 16 cols; lane = (rg = lane>>4, chL = lane&15);
        // rows u = rg + 4j (24 each); fold rg via shfl_xor(16),(32).
        {
            int chL = lane & 15, rg = lane >> 4;
            int ch = wsub * 16 + chL;
            float acc[NM] = {0.f,0.f,0.f,0.f,0.f,0.f};
            #pragma unroll 8
            for (int j = 0; j < 24; ++j) {
                int u = rg + 4 * j;
                float kv = S[u * KP2 + ch];
                #pragma unroll
                for (int mo = 0; mo < NM; ++mo) acc[mo] += S[SOFF + mo * 96 + u] * kv;
            }
            #pragma unroll
            for (int mo = 0; mo < NM; ++mo) {
                float v = acc[mo];
                v += __shfl_xor(v, 16, 64);
                v += __shfl_xor(v, 32, 64);
                if (rg == 0) po[(size_t)plane * (NM * NCH) + mo * NCH + ch] = v;
            }
        }
    }
    __threadfence();
    grid.sync();
    __threadfence();

    // ================= Phase 4: combine + proj + residual (384 tasks) =====
    {
        bool act = (sub == 0) && (bc < 384);
        int cgrp = bc & 3, bm = bc >> 2;
        int b = bm / NM, m = bm - b * NM;
        float* orow = S + QOFF;              // 512
        float* part = S + QOFF + 512;        // 144
        if (act) {
            for (int i = ttid; i < NINNER; i += 256) {
                int h = i >> 6, ch = i & 63;
                int base = (b * NHEADS + h) * NCHUNK;
                float num = 0.f, den = 0.f;
                #pragma unroll
                for (int cu = 0; cu < NCHUNK; ++cu) {
                    num += po[(size_t)(base + cu) * (NM * NCH) + m * NCH + ch];
                    den += ps[(base + cu) * NM + m];
                }
                orow[i] = num / den;
            }
        }
        __syncthreads();
        int ks = ttid / 48;
        int colL = ttid - ks * 48;
        float a = 0.f;
        int col = cgrp * 48 + ((ttid < 192) ? colL : 0);
        if (act && ttid < 192) {
            int i0 = ks * 128;
            #pragma unroll 8
            for (int i = i0; i < i0 + 128; ++i) a += orow[i] * wo[i * ND + col];
            if (ks > 0) part[(ks - 1) * 48 + colL] = a;
        }
        __syncthreads();
        if (act && ttid < 48) {
            float tot = a + part[colL] + part[48 + colL] + part[96 + colL]
                      + bo[col] + znew[bm * ND + col];
            out[bm * ND + col] = tot;
        }
    }
}

// =====================================================================
// Fallback path: the verified 36.7us four-kernel pipeline (R4, verbatim)
// =====================================================================
__global__ __launch_bounds__(256) void pool_kernel(const float* __restrict__ x,
                                                   float* __restrict__ xmean) {
    int bc = blockIdx.x;
    const float4* p = (const float4*)(x + (size_t)bc * PLANE);
    int tid = threadIdx.x;
    float acc[6] = {0.f,0.f,0.f,0.f,0.f,0.f};
    #pragma unroll
    for (int k = 0; k < 6; ++k) {
        int idx4 = tid + k * 256;
        int hh = idx4 / 24;
        int w4 = idx4 - hh * 24;
        int j = (hh >> 5) * 3 + (w4 >> 3);
        float4 v = p[idx4];
        acc[j] += v.x + v.y + v.z + v.w;
    }
    int lane = tid & 63, wave = tid >> 6;
    #pragma unroll
    for (int j = 0; j < 6; ++j) {
        float v = acc[j];
        for (int off = 32; off > 0; off >>= 1) v += __shfl_down(v, off, 64);
        acc[j] = v;
    }
    __shared__ float part[4][6];
    if (lane == 0) {
        #pragma unroll
        for (int j = 0; j < 6; ++j) part[wave][j] = acc[j];
    }
    __syncthreads();
    if (tid < 6) {
        float s = part[0][tid] + part[1][tid] + part[2][tid] + part[3][tid];
        xmean[bc * 6 + tid] = s * (1.0f / 1024.0f);
    }
}

__global__ __launch_bounds__(256) void zq_kernel(const float* __restrict__ z,
                                                 const float* __restrict__ conv_w,
                                                 const float* __restrict__ conv_b,
                                                 const float* __restrict__ wq,
                                                 const float* __restrict__ bq,
                                                 const float* __restrict__ xmean,
                                                 float* __restrict__ znew,
                                                 float* __restrict__ qr) {
    int blk = blockIdx.x;
    int cgrp = blk & 7, bm = blk >> 3;
    int b = bm / NM, m = bm - b * NM;
    int tid = threadIdx.x;
    __shared__ float xm[NC];
    __shared__ float zn[ND];
    __shared__ float qpart[3][64];
    if (tid < NC) xm[tid] = xmean[(b * NC + tid) * NM + m];
    __syncthreads();
    if (tid < ND) {
        float a = conv_b[tid];
        const float* wr = conv_w + tid * NC;
        #pragma unroll 16
        for (int c = 0; c < NC; ++c) a += wr[c] * xm[c];
        float v = z[bm * ND + tid] + a;
        zn[tid] = v;
        if (cgrp == 0) znew[bm * ND + tid] = v;
    }
    __syncthreads();
    int colL = tid & 63, ks = tid >> 6;
    int col = cgrp * 64 + colL;
    float a = (ks == 0) ? bq[col] : 0.f;
    int d0 = ks * 48;
    #pragma unroll 8
    for (int d = d0; d < d0 + 48; ++d) a += zn[d] * wq[d * NINNER + col];
    if (ks > 0) qpart[ks - 1][colL] = a;
    __syncthreads();
    if (ks == 0) {
        float tot = a + qpart[0][colL] + qpart[1][colL] + qpart[2][colL];
        int t = m * 8 + cgrp;
        qr[b * (48 * 64) + t * 64 + colL] = tot;
    }
}

__global__ __launch_bounds__(256, 4) void fattn_kernel(const float* __restrict__ x,
                                                       const float* __restrict__ qr,
                                                       float* __restrict__ po,
                                                       float* __restrict__ ps) {
    int blk = blockIdx.x;
    int chunk = blk & 7, bh = blk >> 3;
    int head = bh & 7, b = bh >> 3;
    int tid = threadIdx.x;
    __shared__ float k_lds[CK][KP];
    __shared__ float q_lds[NM][KP];
    __shared__ float s_lds[NM][SP];
    __shared__ float pvp[3][NM][NCH];
    const float* kbase = x + (size_t)b * XB + (size_t)(head * NKEY + chunk * CK) * NCH;

    for (int i = tid; i < NM * NCH; i += 256) {
        int mi = i >> 6, ch = i & 63;
        q_lds[mi][ch] = qr[b * (48 * 64) + (head * NM + mi) * 64 + ch];
    }
    const float4* k4 = (const float4*)kbase;
    #pragma unroll
    for (int r = 0; r < 6; ++r) {
        int i = tid + r * 256;
        int row = i >> 4, c4 = i & 15;
        float4 v = k4[i];
        *(float4*)&k_lds[row][c4 * 4] = v;
    }
    __syncthreads();

    if (tid < 48) {
        int t = tid >> 1, mip = (tid & 1) * 3;
        float a[4][3];
        #pragma unroll
        for (int j = 0; j < 4; ++j) { a[j][0] = 0.f; a[j][1] = 0.f; a[j][2] = 0.f; }
        #pragma unroll 4
        for (int c = 0; c < 16; ++c) {
            float4 q0 = *(const float4*)&q_lds[mip + 0][c * 4];
            float4 q1 = *(const float4*)&q_lds[mip + 1][c * 4];
            float4 q2 = *(const float4*)&q_lds[mip + 2][c * 4];
            #pragma unroll
            for (int j = 0; j < 4; ++j) {
                float4 kv = *(const float4*)&k_lds[t + 24 * j][c * 4];
                a[j][0] += kv.x*q0.x + kv.y*q0.y + kv.z*q0.z + kv.w*q0.w;
                a[j][1] += kv.x*q1.x + kv.y*q1.y + kv.z*q1.z + kv.w*q1.w;
                a[j][2] += kv.x*q2.x + kv.y*q2.y + kv.z*q2.z + kv.w*q2.w;
            }
        }
        #pragma unroll
        for (int j = 0; j < 4; ++j) {
            s_lds[mip + 0][t + 24 * j] = __expf(a[j][0] * 0.125f);
            s_lds[mip + 1][t + 24 * j] = __expf(a[j][1] * 0.125f);
            s_lds[mip + 2][t + 24 * j] = __expf(a[j][2] * 0.125f);
        }
    }
    __syncthreads();

    int lane = tid & 63, wave = tid >> 6;
    #pragma unroll
    for (int rb = 0; rb < 2; ++rb) {
        int mi = rb * 4 + wave;
        if (mi < NM) {
            float v = s_lds[mi][lane] + ((lane < 32) ? s_lds[mi][64 + lane] : 0.f);
            for (int msk = 1; msk < 64; msk <<= 1) v += __shfl_xor(v, msk, 64);
            if (lane == 0) ps[blk * NM + mi] = v;
        }
    }

    float acc[NM] = {0.f,0.f,0.f,0.f,0.f,0.f};
    {
        int uq = tid >> 6, ch = tid & 63;
        int u0 = uq * 24;
        #pragma unroll
        for (int ub = 0; ub < 6; ++ub) {
            float4 s0 = *(const float4*)&s_lds[0][u0 + ub * 4];
            float4 s1 = *(const float4*)&s_lds[1][u0 + ub * 4];
            float4 s2 = *(const float4*)&s_lds[2][u0 + ub * 4];
            float4 s3 = *(const float4*)&s_lds[3][u0 + ub * 4];
            float4 s4 = *(const float4*)&s_lds[4][u0 + ub * 4];
            float4 s5 = *(const float4*)&s_lds[5][u0 + ub * 4];
            float kv0 = k_lds[u0 + ub * 4 + 0][ch];
            float kv1 = k_lds[u0 + ub * 4 + 1][ch];
            float kv2 = k_lds[u0 + ub * 4 + 2][ch];
            float kv3 = k_lds[u0 + ub * 4 + 3][ch];
            acc[0] += s0.x*kv0 + s0.y*kv1 + s0.z*kv2 + s0.w*kv3;
            acc[1] += s1.x*kv0 + s1.y*kv1 + s1.z*kv2 + s1.w*kv3;
            acc[2] += s2.x*kv0 + s2.y*kv1 + s2.z*kv2 + s2.w*kv3;
            acc[3] += s3.x*kv0 + s3.y*kv1 + s3.z*kv2 + s3.w*kv3;
            acc[4] += s4.x*kv0 + s4.y*kv1 + s4.z*kv2 + s4.w*kv3;
            acc[5] += s5.x*kv0 + s5.y*kv1 + s5.z*kv2 + s5.w*kv3;
        }
        if (uq > 0) {
            #pragma unroll
            for (int mo = 0; mo < NM; ++mo) pvp[uq - 1][mo][ch] = acc[mo];
        }
    }
    __syncthreads();
    if (tid < 64) {
        int ch = tid;
        #pragma unroll
        for (int mo = 0; mo < NM; ++mo) {
            float o = acc[mo] + pvp[0][mo][ch] + pvp[1][mo][ch] + pvp[2][mo][ch];
            po[(size_t)blk * (NM * NCH) + mo * NCH + ch] = o;
        }
    }
}

__global__ __launch_bounds__(256) void proj_kernel(const float* __restrict__ znew,
                                                   const float* __restrict__ po,
                                                   const float* __restrict__ ps,
                                                   const float* __restrict__ wo,
                                                   const float* __restrict__ bo,
                                                   float* __restrict__ out) {
    int blk = blockIdx.x;
    int cgrp = blk & 3, bm = blk >> 2;
    int b = bm / NM, m = bm - b * NM;
    int tid = threadIdx.x;
    __shared__ float orow[NINNER];
    __shared__ float part[3][48];

    for (int i = tid; i < NINNER; i += 256) {
        int h = i >> 6, ch = i & 63;
        int base = (b * NHEADS + h) * NCHUNK;
        float num = 0.f, den = 0.f;
        #pragma unroll
        for (int c = 0; c < NCHUNK; ++c) {
            num += po[(size_t)(base + c) * (NM * NCH) + m * NCH + ch];
            den += ps[(base + c) * NM + m];
        }
        orow[i] = num / den;
    }
    __syncthreads();

    int ks = tid / 48;
    int colL = tid - ks * 48;
    float a = 0.f;
    int col = cgrp * 48 + ((tid < 192) ? colL : 0);
    if (tid < 192) {
        int i0 = ks * 128;
        #pragma unroll 8
        for (int i = i0; i < i0 + 128; ++i) a += orow[i] * wo[i * ND + col];
        if (ks > 0) part[ks - 1][colL] = a;
    }
    __syncthreads();
    if (tid < 48) {
        float tot = a + part[0][colL] + part[1][colL] + part[2][colL]
                  + bo[col] + znew[bm * ND + col];
        out[bm * ND + col] = tot;
    }
}

extern "C" void kernel_launch(void* const* d_in, const int* in_sizes, int n_in,
                              void* d_out, int out_size, void* d_ws, size_t ws_size,
                              hipStream_t stream) {
    const float* x      = (const float*)d_in[0];
    const float* z      = (const float*)d_in[1];
    const float* conv_w = (const float*)d_in[2];
    const float* conv_b = (const float*)d_in[3];
    const float* wq     = (const float*)d_in[4];
    const float* bq     = (const float*)d_in[5];
    const float* wo     = (const float*)d_in[6];
    const float* bo     = (const float*)d_in[7];
    float* out = (float*)d_out;

    float* ws    = (float*)d_ws;
    float* xmean = ws;              // 16*64*6          = 6144
    float* znew  = ws + 6144;       // 16*6*192         = 18432
    float* qr    = ws + 24576;      // 16*48*64         = 49152
    float* po    = ws + 73728;      // 1024*6*64        = 393216
    float* ps    = ws + 466944;     // 1024*6           = 6144

    // Gate: cooperative launch needs all 512 blocks co-resident (>=2/CU).
    static int coop_state = -1;     // -1 unknown, 1 usable, 0 fallback
    if (coop_state == -1) {
        int nb = 0;
        hipError_t e = hipOccupancyMaxActiveBlocksPerMultiprocessor(
            &nb, (const void*)fused_kernel, 512, 0);
        coop_state = (e == hipSuccess && nb >= 2) ? 1 : 0;
    }
    if (coop_state == 1) {
        void* args[] = {
            (void*)&x, (void*)&z, (void*)&conv_w, (void*)&conv_b,
            (void*)&wq, (void*)&bq, (void*)&wo, (void*)&bo,
            (void*)&xmean, (void*)&znew, (void*)&qr, (void*)&po, (void*)&ps,
            (void*)&out
        };
        hipError_t e = hipLaunchCooperativeKernel((const void*)fused_kernel,
                                                  dim3(512), dim3(512),
                                                  args, 0, stream);
        if (e == hipSuccess) return;
        coop_state = 0;             // fall through to the proven path
    }

    pool_kernel<<<NB*NC, 256, 0, stream>>>(x, xmean);
    zq_kernel<<<NB*NM*8, 256, 0, stream>>>(z, conv_w, conv_b, wq, bq, xmean, znew, qr);
    fattn_kernel<<<NB*NHEADS*NCHUNK, 256, 0, stream>>>(x, qr, po, ps);
    proj_kernel<<<NB*NM*4, 256, 0, stream>>>(znew, po, ps, wo, bo, out);
}